// Round 5
// baseline (681.109 us; speedup 1.0000x reference)
//
#include <hip/hip_runtime.h>
#include <math.h>

#define B_SZ 24
#define T_SZ 8192
#define IN_SZ 55
#define H_SZ 110
#define OUT_SZ 23

constexpr int CHUNK = 512;   // scan chunk length
constexpr int WARM  = 256;   // warmup steps (0.9^256 ~ 2e-12 -> exact to fp32)
constexpr int PF    = 16;    // scan prefetch depth (float2 register double-buffer)
constexpr int TAIL  = 768;   // layer-3 truncation: u^768 ~ 1e-35

// X-tile column swizzle: group g = r>>3 shifted by (g>>2)*4 floats.
// Start banks for the 16 fragment addresses: {0,8,16,24,4,12,20,28,...} ->
// every bank exactly 2-way (free) instead of 4-way. Keeps 16B alignment.
__device__ __forceinline__ int xcol(int r) { return r + ((r >> 5) << 2); }

// ---------------------------------------------------------------------------
// GEMM: P[m, j] = bias[j] + sum_k X[row(m), k] * W[j, k]
//   X viewed as (B, T_SZ, K); block m0 covers 128 consecutive rows within one b.
//   P compact (M, 110).
// 128x128 tile (cols padded, j>=110 masked), 8x8 micro-tile,
// K staged in 55-wide slices: LDS = 55*(140+132)*4 = 59.8KB -> 2 blocks/CU.
// ---------------------------------------------------------------------------
template<int K>
__global__ __launch_bounds__(256)
void gemm_kernel(const float* __restrict__ X, const float* __restrict__ W,
                 const float* __restrict__ bias, float* __restrict__ P,
                 int rows_per_b, int t_offset)
{
    __shared__ __align__(16) float Xs[55][140];   // k-major, swizzled cols
    __shared__ __align__(16) float Ws[55][132];   // k-major, padded

    const int tid = threadIdx.x;
    const int m0  = blockIdx.x * 128;
    const int b   = m0 / rows_per_b;
    const int tb0 = t_offset + (m0 % rows_per_b);
    const float* Xblk = X + ((size_t)b * T_SZ + tb0) * K;

    const int tx = tid & 15;       // row group
    const int ty = tid >> 4;       // col group
    const int r0 = tx * 8;
    const int c0 = ty * 8;
    const int r0s = xcol(r0);      // swizzled base col (r0 and r0+4 share group)

    float acc[8][8];
    #pragma unroll
    for (int ci = 0; ci < 8; ci++) {
        const int c = c0 + ci;
        const float bb = (c < H_SZ) ? bias[c] : 0.f;
        #pragma unroll
        for (int ri = 0; ri < 8; ri++) acc[ri][ci] = bb;
    }

    for (int kb = 0; kb < K; kb += 55) {
        __syncthreads();   // protect previous slice's reads
        // stage W slice: Ws[kk][j] = W[j][kb+kk]
        for (int idx = tid; idx < H_SZ * 55; idx += 256) {
            const int j = idx / 55, kk = idx - j * 55;
            Ws[kk][j] = W[(size_t)j * K + kb + kk];
        }
        // zero-pad cols 110..131
        for (int idx = tid; idx < 55 * 22; idx += 256) {
            const int kk = idx / 22, j = H_SZ + (idx - kk * 22);
            Ws[kk][j] = 0.f;
        }
        // stage X slice transposed+swizzled: Xs[kk][xcol(r)] = Xblk[r][kb+kk]
        for (int idx = tid; idx < 128 * 55; idx += 256) {
            const int r = idx / 55, kk = idx - r * 55;
            Xs[kk][xcol(r)] = Xblk[(size_t)r * K + kb + kk];
        }
        __syncthreads();

        #pragma unroll 2
        for (int kk = 0; kk < 55; kk++) {
            const float4 xa = *reinterpret_cast<const float4*>(&Xs[kk][r0s]);
            const float4 xb = *reinterpret_cast<const float4*>(&Xs[kk][r0s + 4]);
            const float4 wa = *reinterpret_cast<const float4*>(&Ws[kk][c0]);
            const float4 wb = *reinterpret_cast<const float4*>(&Ws[kk][c0 + 4]);
            const float xv[8] = {xa.x, xa.y, xa.z, xa.w, xb.x, xb.y, xb.z, xb.w};
            const float wv[8] = {wa.x, wa.y, wa.z, wa.w, wb.x, wb.y, wb.z, wb.w};
            #pragma unroll
            for (int ri = 0; ri < 8; ri++)
                #pragma unroll
                for (int ci = 0; ci < 8; ci++)
                    acc[ri][ci] = fmaf(xv[ri], wv[ci], acc[ri][ci]);
        }
    }

    float* Pout = P + (size_t)m0 * H_SZ;
    #pragma unroll
    for (int ri = 0; ri < 8; ri++) {
        const int r = r0 + ri;
        #pragma unroll
        for (int ci = 0; ci < 8; ci++) {
            const int c = c0 + ci;
            if (c < H_SZ) Pout[(size_t)r * H_SZ + c] = acc[ri][ci];
        }
    }
}

// ---------------------------------------------------------------------------
// Scan: h_t = relu(pre_t + u * h_{t-1}) along t.
// One wave per (b, chunk); lane j < 55 owns channels {2j, 2j+1} via float2.
// Each block handles [t0, t0+chunk) with WARM warmup steps from h=0
// (contraction: u^WARM <= 0.9^256 ~ 2e-12 -> exact to fp32).
// PF-deep float2 register double-buffer hides memory latency.
// Chunk spans (512+256 or 768) are multiples of 2*PF=32 -> no tail code.
// ---------------------------------------------------------------------------
__global__ __launch_bounds__(64)
void scan_kernel(const float* __restrict__ Pre, const float* __restrict__ u_,
                 float* __restrict__ H, int Teff, int chunk)
{
    const int j = threadIdx.x;
    if (j >= 55) return;
    const int b    = blockIdx.y;
    const int t0   = blockIdx.x * chunk;
    const int tw   = (t0 > WARM) ? (t0 - WARM) : 0;
    const int tend = t0 + chunk;

    const float2 u = *reinterpret_cast<const float2*>(u_ + 2 * j);
    const float2* p  = reinterpret_cast<const float2*>(Pre + (size_t)b * Teff * H_SZ) + j;
    float2*       ho = reinterpret_cast<float2*>(H + (size_t)b * Teff * H_SZ) + j;
    // consecutive t: stride 55 float2

    float2 h = {0.f, 0.f};
    float2 Abuf[PF], Bbuf[PF];

    #pragma unroll
    for (int i = 0; i < PF; i++) Abuf[i] = p[(size_t)(tw + i) * 55];

    for (int tb = tw; tb < tend; tb += 2 * PF) {
        #pragma unroll
        for (int i = 0; i < PF; i++) Bbuf[i] = p[(size_t)(tb + PF + i) * 55];
        #pragma unroll
        for (int i = 0; i < PF; i++) {
            h.x = fmaxf(fmaf(u.x, h.x, Abuf[i].x), 0.f);
            h.y = fmaxf(fmaf(u.y, h.y, Abuf[i].y), 0.f);
            const int t = tb + i;
            if (t >= t0) ho[(size_t)t * 55] = h;
        }
        if (tb + 2 * PF < tend) {
            #pragma unroll
            for (int i = 0; i < PF; i++) Abuf[i] = p[(size_t)(tb + 2 * PF + i) * 55];
        }
        #pragma unroll
        for (int i = 0; i < PF; i++) {
            h.x = fmaxf(fmaf(u.x, h.x, Bbuf[i].x), 0.f);
            h.y = fmaxf(fmaf(u.y, h.y, Bbuf[i].y), 0.f);
            const int t = tb + PF + i;
            if (t >= t0) ho[(size_t)t * 55] = h;
        }
    }
}

// ---------------------------------------------------------------------------
// Head: last = h3[:, -1, :]; logits = last @ Wo^T + bo; out = log_softmax.
// h3 stored compact (B, TAIL, 110); last row index = b*TAIL + (TAIL-1).
// ---------------------------------------------------------------------------
__global__ __launch_bounds__(256)
void head_kernel(const float* __restrict__ H3, const float* __restrict__ Wo,
                 const float* __restrict__ bo, float* __restrict__ out)
{
    __shared__ float last[B_SZ][112];
    __shared__ float wsh[OUT_SZ][112];
    __shared__ float logits[B_SZ][32];
    const int tid = threadIdx.x;

    for (int idx = tid; idx < B_SZ * H_SZ; idx += 256) {
        const int b = idx / H_SZ, j = idx - b * H_SZ;
        last[b][j] = H3[((size_t)b * TAIL + (TAIL - 1)) * H_SZ + j];
    }
    for (int idx = tid; idx < OUT_SZ * H_SZ; idx += 256) {
        const int o = idx / H_SZ, j = idx - o * H_SZ;
        wsh[o][j] = Wo[idx];
    }
    __syncthreads();

    // B*OUT = 552 > 256 threads -> stride, not mask (round-3 bug fix).
    for (int idx = tid; idx < B_SZ * OUT_SZ; idx += 256) {
        const int b = idx / OUT_SZ, o = idx - b * OUT_SZ;
        float s = bo[o];
        for (int k = 0; k < H_SZ; k++) s = fmaf(last[b][k], wsh[o][k], s);
        logits[b][o] = s;
    }
    __syncthreads();

    if (tid < B_SZ) {
        const int b = tid;
        float m = -1e30f;
        for (int o = 0; o < OUT_SZ; o++) m = fmaxf(m, logits[b][o]);
        float sum = 0.f;
        for (int o = 0; o < OUT_SZ; o++) sum += expf(logits[b][o] - m);
        const float lse = m + logf(sum);
        for (int o = 0; o < OUT_SZ; o++) out[b * OUT_SZ + o] = logits[b][o] - lse;
    }
}

// ---------------------------------------------------------------------------
extern "C" void kernel_launch(void* const* d_in, const int* in_sizes, int n_in,
                              void* d_out, int out_size, void* d_ws, size_t ws_size,
                              hipStream_t stream)
{
    const float* x  = (const float*)d_in[0];  // (B, T, 55)
    const float* w0 = (const float*)d_in[1];  // (110, 55)
    const float* w1 = (const float*)d_in[2];  // (110, 110)
    const float* w2 = (const float*)d_in[3];  // (110, 110)
    const float* w3 = (const float*)d_in[4];  // (110, 110)
    const float* u  = (const float*)d_in[5];  // (4, 110)
    const float* bi = (const float*)d_in[6];  // (4, 110)
    const float* wo = (const float*)d_in[7];  // (23, 110)
    const float* bo = (const float*)d_in[8];  // (23,)
    float* out = (float*)d_out;

    const size_t act_elems = (size_t)B_SZ * T_SZ * H_SZ;
    float* P = (float*)d_ws;        // pre-activations (86.5 MB)
    float* A = P + act_elems;       // hidden state    (86.5 MB)

    const dim3 blk(256);
    const dim3 sblk(64);
    const dim3 sgrid(T_SZ / CHUNK, B_SZ);

    // layer 0 (K=55)
    gemm_kernel<IN_SZ><<<dim3((B_SZ * T_SZ) / 128), blk, 0, stream>>>(x, w0, bi, P, T_SZ, 0);
    scan_kernel<<<sgrid, sblk, 0, stream>>>(P, u, A, T_SZ, CHUNK);
    // layer 1
    gemm_kernel<H_SZ><<<dim3((B_SZ * T_SZ) / 128), blk, 0, stream>>>(A, w1, bi + H_SZ, P, T_SZ, 0);
    scan_kernel<<<sgrid, sblk, 0, stream>>>(P, u + H_SZ, A, T_SZ, CHUNK);
    // layer 2
    gemm_kernel<H_SZ><<<dim3((B_SZ * T_SZ) / 128), blk, 0, stream>>>(A, w2, bi + 2 * H_SZ, P, T_SZ, 0);
    scan_kernel<<<sgrid, sblk, 0, stream>>>(P, u + 2 * H_SZ, A, T_SZ, CHUNK);
    // layer 3: only the last TAIL timesteps influence h[T-1] (u^768 ~ 0)
    gemm_kernel<H_SZ><<<dim3((B_SZ * TAIL) / 128), blk, 0, stream>>>(A, w3, bi + 3 * H_SZ, P, TAIL, T_SZ - TAIL);
    scan_kernel<<<dim3(1, B_SZ), sblk, 0, stream>>>(P, u + 3 * H_SZ, A, TAIL, TAIL);
    // head
    head_kernel<<<dim3(1), blk, 0, stream>>>(A, wo, bo, out);
}

// Round 9
// 411.224 us; speedup vs baseline: 1.6563x; 1.6563x over previous
//
#include <hip/hip_runtime.h>
#include <math.h>

#define B_SZ 24
#define T_SZ 8192
#define IN_SZ 55
#define H_SZ 110
#define OUT_SZ 23

constexpr int CHUNK = 512;   // scan chunk length
constexpr int WARM  = 256;   // warmup steps (0.9^256 ~ 2e-12 -> exact to fp32)
constexpr int PF    = 32;    // scan prefetch depth (float2 double-buffer; 2PF | 512,768)
constexpr int TAIL  = 768;   // layer-3 truncation: u^768 ~ 1e-35

typedef __attribute__((ext_vector_type(8))) _Float16 f16x8;  // 8 fp16 (4 VGPR)
typedef __attribute__((ext_vector_type(4))) float    f32x4;

__device__ __forceinline__ unsigned int pack2h(float x, float y) {
    _Float16 a = (_Float16)x, b = (_Float16)y;   // RNE
    return (unsigned int)__builtin_bit_cast(unsigned short, a) |
           ((unsigned int)__builtin_bit_cast(unsigned short, b) << 16);
}

// ---------------------------------------------------------------------------
// conv_x: x (M,55) f32 -> (M,64) fp16, cols 55..63 zero. One u32 (2 cols)/thread.
// ---------------------------------------------------------------------------
__global__ __launch_bounds__(256)
void conv_x_kernel(const float* __restrict__ x, unsigned int* __restrict__ xh)
{
    const size_t total = (size_t)B_SZ * T_SZ * 32;
    for (size_t i = (size_t)blockIdx.x * 256 + threadIdx.x; i < total;
         i += (size_t)gridDim.x * 256) {
        const size_t r = i >> 5; const int cp = (int)(i & 31);
        const int c0 = 2 * cp, c1 = 2 * cp + 1;
        const float v0 = (c0 < IN_SZ) ? x[r * IN_SZ + c0] : 0.f;
        const float v1 = (c1 < IN_SZ) ? x[r * IN_SZ + c1] : 0.f;
        xh[i] = pack2h(v0, v1);
    }
}

// ---------------------------------------------------------------------------
// MFMA GEMM (fp16 operands, f32 accum): P[m,j] = bias[j] + A[m,:]·W[j,:]
// A: (M, LDA) fp16, zero-padded cols >= KREAL (pads harmless anyway: B-frag
// masks k >= KREAL to 0). W fp32 (110 x KREAL) -> fp16 B-fragments held in
// registers for the whole kernel (64 VGPR). No LDS, no barriers.
// 4 waves/block: wave = (mp, g); g = n-half (j in [g*64, g*64+64)), mp = m parity.
// A-row map: arow = (m/RPB)*T_SZ + t_offset + m%RPB  (compile-time RPB).
// Fragment layout (16x16x32 family, m89-verified): A[r][k]: r=lane&15,
// k=(lane>>4)*8+i; B[k][j]: j=lane&15, k=(lane>>4)*8+i;
// D: col=lane&15 (N), row=(lane>>4)*4+reg (M).
// ---------------------------------------------------------------------------
template<int KREAL, int LDA, int RPB>
__global__ __launch_bounds__(256)
void mfma_gemm(const _Float16* __restrict__ A, const float* __restrict__ W,
               const float* __restrict__ bias, float* __restrict__ P,
               int mt_per_wave, int t_offset)
{
    constexpr int KS = LDA / 32;
    const int tid  = threadIdx.x;
    const int wave = tid >> 6;
    const int lane = tid & 63;
    const int g    = wave & 1;
    const int mp   = wave >> 1;
    const int lrow = lane & 15;
    const int lgrp = lane >> 4;

    // register-resident B fragments (one-time W convert, amortized over m-loop)
    f16x8 bf[4][KS];
    float bb[4];
    #pragma unroll
    for (int nt = 0; nt < 4; nt++) {
        const int j = g * 64 + nt * 16 + lrow;
        bb[nt] = (j < H_SZ) ? bias[j] : 0.f;
        #pragma unroll
        for (int ks = 0; ks < KS; ks++) {
            f16x8 v;
            #pragma unroll
            for (int i = 0; i < 8; i++) {
                const int k = ks * 32 + lgrp * 8 + i;
                const float w = (j < H_SZ && k < KREAL) ? W[(size_t)j * KREAL + k] : 0.f;
                v[i] = (_Float16)w;
            }
            bf[nt][ks] = v;
        }
    }

    const int m_base = blockIdx.x * (mt_per_wave * 32);
    for (int it = 0; it < mt_per_wave; it++) {
        const int m0 = m_base + (it * 2 + mp) * 16;
        const int m  = m0 + lrow;
        const int arow = (m / RPB) * T_SZ + t_offset + (m % RPB);
        const _Float16* ap = A + (size_t)arow * LDA + lgrp * 8;

        f16x8 a[KS];
        #pragma unroll
        for (int ks = 0; ks < KS; ks++) a[ks] = *(const f16x8*)(ap + ks * 32);

        f32x4 acc[4];
        #pragma unroll
        for (int nt = 0; nt < 4; nt++) acc[nt] = (f32x4){bb[nt], bb[nt], bb[nt], bb[nt]};

        #pragma unroll
        for (int ks = 0; ks < KS; ks++)
            #pragma unroll
            for (int nt = 0; nt < 4; nt++)
                acc[nt] = __builtin_amdgcn_mfma_f32_16x16x32_f16(a[ks], bf[nt][ks], acc[nt], 0, 0, 0);

        float* Pout = P + (size_t)m0 * H_SZ;
        #pragma unroll
        for (int nt = 0; nt < 4; nt++) {
            const int col = g * 64 + nt * 16 + lrow;
            if (col < H_SZ) {
                #pragma unroll
                for (int r = 0; r < 4; r++)
                    Pout[(size_t)(lgrp * 4 + r) * H_SZ + col] = acc[nt][r];
            }
        }
    }
}

// ---------------------------------------------------------------------------
// Scan: h_t = relu(pre_t + u * h_{t-1}); reads f32 P (Tin rows/batch, compact),
// writes fp16 h as (b*T_SZ + out_off + t, 128) with cols 110..127 zeroed.
// One wave per (b, chunk); lane j<55 owns channels {2j,2j+1}; WARM warmup from 0.
// ---------------------------------------------------------------------------
__global__ __launch_bounds__(64)
void scan_kernel(const float* __restrict__ Pre, const float* __restrict__ u_,
                 unsigned int* __restrict__ Hh, int Tin, int chunk, int out_off)
{
    const int j = threadIdx.x;
    const bool valid = (j < 55);
    const int jj = valid ? j : 0;
    const int b    = blockIdx.y;
    const int t0   = blockIdx.x * chunk;
    const int tw   = (t0 > WARM) ? (t0 - WARM) : 0;
    const int tend = t0 + chunk;

    float2 u = make_float2(0.f, 0.f);
    if (valid) u = *reinterpret_cast<const float2*>(u_ + 2 * j);
    const float2* p = reinterpret_cast<const float2*>(Pre + (size_t)b * Tin * H_SZ) + jj;
    const size_t orow0 = (size_t)b * T_SZ + out_off;

    float2 h = make_float2(0.f, 0.f);
    float2 Abuf[PF], Bbuf[PF];

    #pragma unroll
    for (int i = 0; i < PF; i++) Abuf[i] = p[(size_t)(tw + i) * 55];

    for (int tb = tw; tb < tend; tb += 2 * PF) {
        #pragma unroll
        for (int i = 0; i < PF; i++) Bbuf[i] = p[(size_t)(tb + PF + i) * 55];
        #pragma unroll
        for (int i = 0; i < PF; i++) {
            h.x = fmaxf(fmaf(u.x, h.x, Abuf[i].x), 0.f);
            h.y = fmaxf(fmaf(u.y, h.y, Abuf[i].y), 0.f);
            const int t = tb + i;
            if (t >= t0)
                Hh[(orow0 + t) * 64 + j] = valid ? pack2h(h.x, h.y) : 0u;
        }
        if (tb + 2 * PF < tend) {
            #pragma unroll
            for (int i = 0; i < PF; i++) Abuf[i] = p[(size_t)(tb + 2 * PF + i) * 55];
        }
        #pragma unroll
        for (int i = 0; i < PF; i++) {
            h.x = fmaxf(fmaf(u.x, h.x, Bbuf[i].x), 0.f);
            h.y = fmaxf(fmaf(u.y, h.y, Bbuf[i].y), 0.f);
            const int t = tb + PF + i;
            if (t >= t0)
                Hh[(orow0 + t) * 64 + j] = valid ? pack2h(h.x, h.y) : 0u;
        }
    }
}

// ---------------------------------------------------------------------------
// Head: last = h3[:, T-1, :] (fp16->f32); logits = last @ Wo^T + bo; log_softmax.
// ---------------------------------------------------------------------------
__global__ __launch_bounds__(256)
void head_kernel(const _Float16* __restrict__ Hh, const float* __restrict__ Wo,
                 const float* __restrict__ bo, float* __restrict__ out)
{
    __shared__ float last[B_SZ][112];
    __shared__ float wsh[OUT_SZ][112];
    __shared__ float logits[B_SZ][32];
    const int tid = threadIdx.x;

    for (int idx = tid; idx < B_SZ * H_SZ; idx += 256) {
        const int b = idx / H_SZ, jj = idx - b * H_SZ;
        last[b][jj] = (float)Hh[((size_t)b * T_SZ + T_SZ - 1) * 128 + jj];
    }
    for (int idx = tid; idx < OUT_SZ * H_SZ; idx += 256) {
        const int oo = idx / H_SZ, jj = idx - oo * H_SZ;
        wsh[oo][jj] = Wo[idx];
    }
    __syncthreads();

    // B*OUT = 552 > 256 threads -> stride, not mask.
    for (int idx = tid; idx < B_SZ * OUT_SZ; idx += 256) {
        const int b = idx / OUT_SZ, o = idx - b * OUT_SZ;
        float s = bo[o];
        for (int k = 0; k < H_SZ; k++) s = fmaf(last[b][k], wsh[o][k], s);
        logits[b][o] = s;
    }
    __syncthreads();

    if (tid < B_SZ) {
        const int b = tid;
        float m = -1e30f;
        for (int o = 0; o < OUT_SZ; o++) m = fmaxf(m, logits[b][o]);
        float sum = 0.f;
        for (int o = 0; o < OUT_SZ; o++) sum += expf(logits[b][o] - m);
        const float lse = m + logf(sum);
        for (int o = 0; o < OUT_SZ; o++) out[b * OUT_SZ + o] = logits[b][o] - lse;
    }
}

// ---------------------------------------------------------------------------
extern "C" void kernel_launch(void* const* d_in, const int* in_sizes, int n_in,
                              void* d_out, int out_size, void* d_ws, size_t ws_size,
                              hipStream_t stream)
{
    const float* x  = (const float*)d_in[0];
    const float* w0 = (const float*)d_in[1];
    const float* w1 = (const float*)d_in[2];
    const float* w2 = (const float*)d_in[3];
    const float* w3 = (const float*)d_in[4];
    const float* u  = (const float*)d_in[5];
    const float* bi = (const float*)d_in[6];
    const float* wo = (const float*)d_in[7];
    const float* bo = (const float*)d_in[8];
    float* out = (float*)d_out;

    // ws: P f32 (M,110) = 86.5MB | A fp16 (M,128) = 50.3MB   (total 136.8MB)
    const size_t M = (size_t)B_SZ * T_SZ;
    float* P = (float*)d_ws;
    _Float16* A = (_Float16*)((char*)d_ws + M * H_SZ * 4);
    unsigned int* Au = (unsigned int*)A;

    // input convert: (M,64) fp16 region at A's start (dead before scan0 writes)
    conv_x_kernel<<<4096, 256, 0, stream>>>(x, Au);
    // layer 0 (K=55, LDA=64)
    mfma_gemm<IN_SZ, 64, T_SZ><<<384, 256, 0, stream>>>(A, w0, bi, P, 16, 0);
    scan_kernel<<<dim3(T_SZ / CHUNK, B_SZ), 64, 0, stream>>>(P, u, Au, T_SZ, CHUNK, 0);
    // layer 1
    mfma_gemm<H_SZ, 128, T_SZ><<<384, 256, 0, stream>>>(A, w1, bi + H_SZ, P, 16, 0);
    scan_kernel<<<dim3(T_SZ / CHUNK, B_SZ), 64, 0, stream>>>(P, u + H_SZ, Au, T_SZ, CHUNK, 0);
    // layer 2
    mfma_gemm<H_SZ, 128, T_SZ><<<384, 256, 0, stream>>>(A, w2, bi + 2 * H_SZ, P, 16, 0);
    scan_kernel<<<dim3(T_SZ / CHUNK, B_SZ), 64, 0, stream>>>(P, u + 2 * H_SZ, Au, T_SZ, CHUNK, 0);
    // layer 3: only last TAIL steps matter (u^768 ~ 0). M' = 24*768 = 18432.
    mfma_gemm<H_SZ, 128, TAIL><<<72, 256, 0, stream>>>(A, w3, bi + 3 * H_SZ, P, 8, T_SZ - TAIL);
    scan_kernel<<<dim3(1, B_SZ), 64, 0, stream>>>(P, u + 3 * H_SZ, Au, TAIL, TAIL, T_SZ - TAIL);
    // head
    head_kernel<<<1, 256, 0, stream>>>(A, wo, bo, out);
}

// Round 10
// 387.868 us; speedup vs baseline: 1.7560x; 1.0602x over previous
//
#include <hip/hip_runtime.h>
#include <math.h>

#define B_SZ 24
#define T_SZ 8192
#define IN_SZ 55
#define H_SZ 110
#define OUT_SZ 23

constexpr int CHUNK = 512;   // scan chunk length
constexpr int WARM  = 128;   // warmup steps (0.9^128 ~ 1.4e-6 << fp16 floor 5e-4)
constexpr int PF    = 32;    // scan prefetch depth (u32/step; 2PF | 512,640,768)
constexpr int TAIL  = 768;   // layer-3 truncation: u^768 ~ 1e-35

typedef __attribute__((ext_vector_type(8))) _Float16 f16x8;  // 8 fp16 (4 VGPR)
typedef __attribute__((ext_vector_type(4))) float    f32x4;

__device__ __forceinline__ unsigned int pack2h(float x, float y) {
    _Float16 a = (_Float16)x, b = (_Float16)y;   // RNE
    return (unsigned int)__builtin_bit_cast(unsigned short, a) |
           ((unsigned int)__builtin_bit_cast(unsigned short, b) << 16);
}
__device__ __forceinline__ float2 unpack2h(unsigned int w) {
    const _Float16 lo = __builtin_bit_cast(_Float16, (unsigned short)(w & 0xffffu));
    const _Float16 hi = __builtin_bit_cast(_Float16, (unsigned short)(w >> 16));
    return make_float2((float)lo, (float)hi);
}

// ---------------------------------------------------------------------------
// conv_x: x (M,55) f32 -> (M,64) fp16, cols 55..63 zero. One u32 (2 cols)/thread.
// ---------------------------------------------------------------------------
__global__ __launch_bounds__(256)
void conv_x_kernel(const float* __restrict__ x, unsigned int* __restrict__ xh)
{
    const size_t total = (size_t)B_SZ * T_SZ * 32;
    for (size_t i = (size_t)blockIdx.x * 256 + threadIdx.x; i < total;
         i += (size_t)gridDim.x * 256) {
        const size_t r = i >> 5; const int cp = (int)(i & 31);
        const int c0 = 2 * cp, c1 = 2 * cp + 1;
        const float v0 = (c0 < IN_SZ) ? x[r * IN_SZ + c0] : 0.f;
        const float v1 = (c1 < IN_SZ) ? x[r * IN_SZ + c1] : 0.f;
        xh[i] = pack2h(v0, v1);
    }
}

// ---------------------------------------------------------------------------
// MFMA GEMM (fp16 in, f32 accum, fp16 packed out): P[m,c]=pair(pre[m,2c],pre[m,2c+1])
// A: (M, LDA) fp16 zero-padded. W fp32 -> register-resident fp16 B-fragments.
// 4 waves/block: wave = (mp, g). No LDS, no barriers.
// Double-buffered A-tile prefetch (a0/a1 ping-pong, mt even -> static indexing).
// D-layout: col=lane&15, row=(lane>>4)*4+reg. Col pairs (2c,2c+1) live in
// adjacent lanes -> one shfl_xor(.,1) + pack on even lanes, u32 store.
// ---------------------------------------------------------------------------
template<int KREAL, int LDA, int RPB>
__global__ __launch_bounds__(256)
void mfma_gemm(const _Float16* __restrict__ A, const float* __restrict__ W,
               const float* __restrict__ bias, unsigned int* __restrict__ P,
               int mt_per_wave, int t_offset)
{
    constexpr int KS = LDA / 32;
    const int tid  = threadIdx.x;
    const int wave = tid >> 6;
    const int lane = tid & 63;
    const int g    = wave & 1;
    const int mp   = wave >> 1;
    const int lrow = lane & 15;
    const int lgrp = lane >> 4;

    // register-resident B fragments
    f16x8 bf[4][KS];
    float bb[4];
    #pragma unroll
    for (int nt = 0; nt < 4; nt++) {
        const int j = g * 64 + nt * 16 + lrow;
        bb[nt] = (j < H_SZ) ? bias[j] : 0.f;
        #pragma unroll
        for (int ks = 0; ks < KS; ks++) {
            f16x8 v;
            #pragma unroll
            for (int i = 0; i < 8; i++) {
                const int k = ks * 32 + lgrp * 8 + i;
                const float w = (j < H_SZ && k < KREAL) ? W[(size_t)j * KREAL + k] : 0.f;
                v[i] = (_Float16)w;
            }
            bf[nt][ks] = v;
        }
    }

    const int m_base = blockIdx.x * (mt_per_wave * 32);

    auto aload = [&](f16x8 (&a)[KS], int it) {
        const int m0 = m_base + (it * 2 + mp) * 16;
        const int m  = m0 + lrow;
        const int arow = (m / RPB) * T_SZ + t_offset + (m % RPB);
        const _Float16* ap = A + (size_t)arow * LDA + lgrp * 8;
        #pragma unroll
        for (int ks = 0; ks < KS; ks++) a[ks] = *(const f16x8*)(ap + ks * 32);
    };
    auto compute_store = [&](f16x8 (&a)[KS], int it) {
        const int m0 = m_base + (it * 2 + mp) * 16;
        f32x4 acc[4];
        #pragma unroll
        for (int nt = 0; nt < 4; nt++) acc[nt] = (f32x4){bb[nt], bb[nt], bb[nt], bb[nt]};
        #pragma unroll
        for (int ks = 0; ks < KS; ks++)
            #pragma unroll
            for (int nt = 0; nt < 4; nt++)
                acc[nt] = __builtin_amdgcn_mfma_f32_16x16x32_f16(a[ks], bf[nt][ks], acc[nt], 0, 0, 0);
        #pragma unroll
        for (int nt = 0; nt < 4; nt++) {
            #pragma unroll
            for (int r = 0; r < 4; r++) {
                const float other = __shfl_xor(acc[nt][r], 1);
                if ((lane & 1) == 0) {   // even lane: own col = lo, neighbor = hi
                    const int c = g * 32 + nt * 8 + (lrow >> 1);
                    P[(size_t)(m0 + lgrp * 4 + r) * 64 + c] = pack2h(acc[nt][r], other);
                }
            }
        }
    };

    f16x8 a0[KS], a1[KS];
    aload(a0, 0);
    for (int it = 0; it < mt_per_wave; it += 2) {   // mt even
        aload(a1, it + 1);
        compute_store(a0, it);
        if (it + 2 < mt_per_wave) aload(a0, it + 2);
        compute_store(a1, it + 1);
    }
}

// ---------------------------------------------------------------------------
// Scan: h_t = relu(pre_t + u * h_{t-1}); reads fp16-pair P (Tin rows/batch,
// (row,64) u32), writes fp16 h as (b*T_SZ + out_off + t, 128), cols>=110 zero.
// One wave per (b, chunk); lane j<55 owns channels {2j,2j+1}; WARM warmup from 0.
// ---------------------------------------------------------------------------
__global__ __launch_bounds__(64)
void scan_kernel(const unsigned int* __restrict__ Pre, const float* __restrict__ u_,
                 unsigned int* __restrict__ Hh, int Tin, int chunk, int out_off)
{
    const int j = threadIdx.x;
    const bool valid = (j < 55);
    const int jj = valid ? j : 0;
    const int b    = blockIdx.y;
    const int t0   = blockIdx.x * chunk;
    const int tw   = (t0 > WARM) ? (t0 - WARM) : 0;
    const int tend = t0 + chunk;

    float2 u = make_float2(0.f, 0.f);
    if (valid) u = *reinterpret_cast<const float2*>(u_ + 2 * j);
    const unsigned int* p = Pre + (size_t)b * Tin * 64 + jj;
    const size_t orow0 = (size_t)b * T_SZ + out_off;

    float2 h = make_float2(0.f, 0.f);
    unsigned int Abuf[PF], Bbuf[PF];

    #pragma unroll
    for (int i = 0; i < PF; i++) Abuf[i] = p[(size_t)(tw + i) * 64];

    for (int tb = tw; tb < tend; tb += 2 * PF) {
        #pragma unroll
        for (int i = 0; i < PF; i++) Bbuf[i] = p[(size_t)(tb + PF + i) * 64];
        #pragma unroll
        for (int i = 0; i < PF; i++) {
            const float2 pv = unpack2h(Abuf[i]);
            h.x = fmaxf(fmaf(u.x, h.x, pv.x), 0.f);
            h.y = fmaxf(fmaf(u.y, h.y, pv.y), 0.f);
            const int t = tb + i;
            if (t >= t0)
                Hh[(orow0 + t) * 64 + j] = valid ? pack2h(h.x, h.y) : 0u;
        }
        if (tb + 2 * PF < tend) {
            #pragma unroll
            for (int i = 0; i < PF; i++) Abuf[i] = p[(size_t)(tb + 2 * PF + i) * 64];
        }
        #pragma unroll
        for (int i = 0; i < PF; i++) {
            const float2 pv = unpack2h(Bbuf[i]);
            h.x = fmaxf(fmaf(u.x, h.x, pv.x), 0.f);
            h.y = fmaxf(fmaf(u.y, h.y, pv.y), 0.f);
            const int t = tb + PF + i;
            if (t >= t0)
                Hh[(orow0 + t) * 64 + j] = valid ? pack2h(h.x, h.y) : 0u;
        }
    }
}

// ---------------------------------------------------------------------------
// Head: last = h3[:, T-1, :] (fp16->f32); logits = last @ Wo^T + bo; log_softmax.
// ---------------------------------------------------------------------------
__global__ __launch_bounds__(256)
void head_kernel(const _Float16* __restrict__ Hh, const float* __restrict__ Wo,
                 const float* __restrict__ bo, float* __restrict__ out)
{
    __shared__ float last[B_SZ][112];
    __shared__ float wsh[OUT_SZ][112];
    __shared__ float logits[B_SZ][32];
    const int tid = threadIdx.x;

    for (int idx = tid; idx < B_SZ * H_SZ; idx += 256) {
        const int b = idx / H_SZ, jj = idx - b * H_SZ;
        last[b][jj] = (float)Hh[((size_t)b * T_SZ + T_SZ - 1) * 128 + jj];
    }
    for (int idx = tid; idx < OUT_SZ * H_SZ; idx += 256) {
        const int oo = idx / H_SZ, jj = idx - oo * H_SZ;
        wsh[oo][jj] = Wo[idx];
    }
    __syncthreads();

    // B*OUT = 552 > 256 threads -> stride, not mask.
    for (int idx = tid; idx < B_SZ * OUT_SZ; idx += 256) {
        const int b = idx / OUT_SZ, o = idx - b * OUT_SZ;
        float s = bo[o];
        for (int k = 0; k < H_SZ; k++) s = fmaf(last[b][k], wsh[o][k], s);
        logits[b][o] = s;
    }
    __syncthreads();

    if (tid < B_SZ) {
        const int b = tid;
        float m = -1e30f;
        for (int o = 0; o < OUT_SZ; o++) m = fmaxf(m, logits[b][o]);
        float sum = 0.f;
        for (int o = 0; o < OUT_SZ; o++) sum += expf(logits[b][o] - m);
        const float lse = m + logf(sum);
        for (int o = 0; o < OUT_SZ; o++) out[b * OUT_SZ + o] = logits[b][o] - lse;
    }
}

// ---------------------------------------------------------------------------
extern "C" void kernel_launch(void* const* d_in, const int* in_sizes, int n_in,
                              void* d_out, int out_size, void* d_ws, size_t ws_size,
                              hipStream_t stream)
{
    const float* x  = (const float*)d_in[0];
    const float* w0 = (const float*)d_in[1];
    const float* w1 = (const float*)d_in[2];
    const float* w2 = (const float*)d_in[3];
    const float* w3 = (const float*)d_in[4];
    const float* u  = (const float*)d_in[5];
    const float* bi = (const float*)d_in[6];
    const float* wo = (const float*)d_in[7];
    const float* bo = (const float*)d_in[8];
    float* out = (float*)d_out;

    // ws: P u32 (M,64) = 50.3MB | A fp16 (M,128) = 50.3MB   (total 100.7MB)
    const size_t M = (size_t)B_SZ * T_SZ;
    unsigned int* P = (unsigned int*)d_ws;
    _Float16* A = (_Float16*)((char*)d_ws + M * 64 * 4);
    unsigned int* Au = (unsigned int*)A;

    // input convert: (M,64) fp16 region at A's start (dead before scan0 writes)
    conv_x_kernel<<<4096, 256, 0, stream>>>(x, Au);
    // layer 0 (K=55, LDA=64)
    mfma_gemm<IN_SZ, 64, T_SZ><<<768, 256, 0, stream>>>(A, w0, bi, P, 8, 0);
    scan_kernel<<<dim3(T_SZ / CHUNK, B_SZ), 64, 0, stream>>>(P, u, Au, T_SZ, CHUNK, 0);
    // layer 1
    mfma_gemm<H_SZ, 128, T_SZ><<<768, 256, 0, stream>>>(A, w1, bi + H_SZ, P, 8, 0);
    scan_kernel<<<dim3(T_SZ / CHUNK, B_SZ), 64, 0, stream>>>(P, u + H_SZ, Au, T_SZ, CHUNK, 0);
    // layer 2
    mfma_gemm<H_SZ, 128, T_SZ><<<768, 256, 0, stream>>>(A, w2, bi + 2 * H_SZ, P, 8, 0);
    scan_kernel<<<dim3(T_SZ / CHUNK, B_SZ), 64, 0, stream>>>(P, u + 2 * H_SZ, Au, T_SZ, CHUNK, 0);
    // layer 3: only last TAIL steps matter (u^768 ~ 0). M' = 24*768 = 18432.
    mfma_gemm<H_SZ, 128, TAIL><<<72, 256, 0, stream>>>(A, w3, bi + 3 * H_SZ, P, 8, T_SZ - TAIL);
    scan_kernel<<<dim3(1, B_SZ), 64, 0, stream>>>(P, u + 3 * H_SZ, Au, TAIL, TAIL, T_SZ - TAIL);
    // head
    head_kernel<<<1, 256, 0, stream>>>(A, wo, bo, out);
}